// Round 2
// baseline (474.465 us; speedup 1.0000x reference)
//
#include <hip/hip_runtime.h>
#include <math.h>

// Problem constants
#define BB 128
#define SS 512
#define NN 32
#define DD 512
#define HH 2
#define MM (BB * NN)          // 4096 rows
#define DSQ (DD * DD)         // 262144

typedef short bf16x8 __attribute__((ext_vector_type(8)));
typedef float f32x4 __attribute__((ext_vector_type(4)));

__device__ __forceinline__ unsigned short f2bf(float f) {
    unsigned int u = __float_as_uint(f);
    u += 0x7fffu + ((u >> 16) & 1u);
    return (unsigned short)(u >> 16);
}
__device__ __forceinline__ float bf2f(unsigned short h) {
    return __uint_as_float(((unsigned int)h) << 16);
}
__device__ __forceinline__ void g2l16(const void* gp, void* lp) {
    __builtin_amdgcn_global_load_lds(
        (const __attribute__((address_space(1))) void*)gp,
        (__attribute__((address_space(3))) void*)lp, 16, 0, 0);
}

// ---------------------------------------------------------------------------
// adj + slot map fused: g_gt/g_lt [B,32,32] row-normalized; slot[b][s]
// ---------------------------------------------------------------------------
__global__ __launch_bounds__(256) void adj_k(const int* __restrict__ order,
                                             const int* __restrict__ pos,
                                             float* __restrict__ g_gt,
                                             float* __restrict__ g_lt,
                                             int* __restrict__ slot) {
    int b = blockIdx.x;
    __shared__ int ord[NN];
    __shared__ float sgt[NN][NN + 1];
    __shared__ float slt[NN][NN + 1];
    __shared__ float rs_gt[NN], rs_lt[NN];
    int tid = threadIdx.x;
    slot[b * SS + tid] = -1;
    slot[b * SS + 256 + tid] = -1;
    if (tid < NN) ord[tid] = order[b * NN + tid];
    __syncthreads();
    for (int q = 0; q < 4; ++q) {
        int idx = tid + 256 * q;
        int n = idx >> 5, m = idx & 31;
        bool valid = (ord[n] > 0) && (ord[m] > 0) && (n != m);
        float eye = (n == m) ? 1.f : 0.f;
        bool gt = ord[n] > ord[m];
        sgt[n][m] = ((valid && gt) ? 1.f : 0.f) + eye;
        slt[n][m] = ((valid && !gt) ? 1.f : 0.f) + eye;
    }
    __syncthreads();
    if (tid < NN) {
        float s1 = 0.f, s2 = 0.f;
        for (int m = 0; m < NN; ++m) { s1 += sgt[tid][m]; s2 += slt[tid][m]; }
        rs_gt[tid] = s1; rs_lt[tid] = s2;
    }
    __syncthreads();
    for (int q = 0; q < 4; ++q) {
        int idx = tid + 256 * q;
        int n = idx >> 5, m = idx & 31;
        g_gt[b * 1024 + idx] = sgt[n][m] / rs_gt[n];
        g_lt[b * 1024 + idx] = slt[n][m] / rs_lt[n];
    }
    if (tid < NN) {
        int p = pos[b * NN + tid];
        if (p >= 0) slot[b * SS + p] = tid;
    }
}

// ---------------------------------------------------------------------------
// Weight prep (transpose + bf16) + gate-weight combine, one kernel.
// ---------------------------------------------------------------------------
struct WSfull { const float* s[12]; int slot[12]; const float* w_g; };

__global__ __launch_bounds__(256) void wprep_k(WSfull w, unsigned short* __restrict__ Wt) {
    int which = blockIdx.x;
    int tile = blockIdx.y;
    int tr = (tile >> 3) * 64, tc = (tile & 7) * 64;
    __shared__ float c1[64][65];
    __shared__ float c2[64][65];
    int lc = threadIdx.x & 63, g4 = threadIdx.x >> 6;
    if (which < 12) {
        const float* src = w.s[which];
        unsigned short* dst = Wt + (size_t)w.slot[which] * DSQ;
        for (int i = 0; i < 16; ++i) {
            int lr = g4 * 16 + i;
            c1[lr][lc] = src[(size_t)(tr + lr) * DD + tc + lc];
        }
        __syncthreads();
        for (int i = 0; i < 16; ++i) {
            int lr = g4 * 16 + i;
            dst[(size_t)(tc + lr) * DD + tr + lc] = f2bf(c1[lc][lr]);
        }
    } else {
        int h = which - 12;
        const float* base = w.w_g + (size_t)h * 4 * DSQ;
        for (int i = 0; i < 16; ++i) {
            int lr = g4 * 16 + i;
            int k = tr + lr, n = tc + lc;
            float a  = base[(size_t)k * DD + n];
            float b2 = base[(size_t)(DD + k) * DD + n];
            float c  = base[(size_t)(2 * DD + k) * DD + n];
            float d4 = base[(size_t)(3 * DD + k) * DD + n];
            c1[lr][lc] = a + c + d4;
            c2[lr][lc] = b2 + c - d4;
        }
        __syncthreads();
        unsigned short* d1 = Wt + (size_t)(h * 8 + 4) * DSQ;
        unsigned short* d2 = Wt + (size_t)(h * 8 + 5) * DSQ;
        for (int i = 0; i < 16; ++i) {
            int lr = g4 * 16 + i;
            d1[(size_t)(tc + lr) * DD + tr + lc] = f2bf(c1[lc][lr]);
            d2[(size_t)(tc + lr) * DD + tr + lc] = f2bf(c2[lc][lr]);
        }
    }
}

// fp32 -> bf16 conversion (num_enc -> node0)
__global__ void conv_k(const float* __restrict__ x, unsigned short* __restrict__ o) {
    size_t i = ((size_t)blockIdx.x * 256 + threadIdx.x) * 4;
    float4 v = *(const float4*)(x + i);
    ushort4 r;
    r.x = f2bf(v.x); r.y = f2bf(v.y); r.z = f2bf(v.z); r.w = f2bf(v.w);
    *(ushort4*)(o + i) = r;
}

// ---------------------------------------------------------------------------
// mix_k: Z[b*32+n, :] = sum_m G[b,n,m] * X[b*32+m, :]   (fp32 accum, bf16 out)
// grid (BB, DD/128, 2): z=0 -> (g_gt, X1, Z1); z=1 -> (g_lt, X2, Z2)
// ---------------------------------------------------------------------------
__global__ __launch_bounds__(256) void mix_k(const float* __restrict__ g_gt,
                                             const float* __restrict__ g_lt,
                                             const unsigned short* __restrict__ X1,
                                             const unsigned short* __restrict__ X2,
                                             unsigned short* __restrict__ Z1,
                                             unsigned short* __restrict__ Z2) {
    const int b = blockIdx.x;
    const int dc = blockIdx.y * 128;
    const float* G = blockIdx.z ? g_lt : g_gt;
    const unsigned short* X = blockIdx.z ? X2 : X1;
    unsigned short* Z = blockIdx.z ? Z2 : Z1;
    __shared__ float gs[NN * 33];        // padded stride 33 -> conflict-free
    __shared__ float xs[NN][128];
    const int t = threadIdx.x;
    {
        float4 v = ((const float4*)(G + (size_t)b * 1024))[t];
        int n = t >> 3, m0 = (t & 7) * 4;
        float* gp = gs + n * 33 + m0;
        gp[0] = v.x; gp[1] = v.y; gp[2] = v.z; gp[3] = v.w;
    }
#pragma unroll
    for (int q = 0; q < 2; ++q) {
        int e = t + 256 * q;
        int m = e >> 4, c = (e & 15) * 8;
        const unsigned short* src = X + ((size_t)(b * NN + m)) * DD + dc + c;
        ushort4 lo = *(const ushort4*)src;
        ushort4 hi = *(const ushort4*)(src + 4);
        float* xp = &xs[m][c];
        xp[0] = bf2f(lo.x); xp[1] = bf2f(lo.y); xp[2] = bf2f(lo.z); xp[3] = bf2f(lo.w);
        xp[4] = bf2f(hi.x); xp[5] = bf2f(hi.y); xp[6] = bf2f(hi.z); xp[7] = bf2f(hi.w);
    }
    __syncthreads();
    const int n = t >> 3;
    const int c0 = (t & 7) * 16;
    f32x4 r0 = {0.f, 0.f, 0.f, 0.f}, r1 = r0, r2 = r0, r3 = r0;
#pragma unroll
    for (int m = 0; m < NN; ++m) {
        float gv = gs[n * 33 + m];
        const float* xr = &xs[m][c0];
        r0 += gv * *(const f32x4*)(xr);
        r1 += gv * *(const f32x4*)(xr + 4);
        r2 += gv * *(const f32x4*)(xr + 8);
        r3 += gv * *(const f32x4*)(xr + 12);
    }
    unsigned short* dst = Z + ((size_t)(b * NN + n)) * DD + dc + c0;
    ushort4 o0, o1, o2, o3;
    o0.x = f2bf(r0.x); o0.y = f2bf(r0.y); o0.z = f2bf(r0.z); o0.w = f2bf(r0.w);
    o1.x = f2bf(r1.x); o1.y = f2bf(r1.y); o1.z = f2bf(r1.z); o1.w = f2bf(r1.w);
    o2.x = f2bf(r2.x); o2.y = f2bf(r2.y); o2.z = f2bf(r2.z); o2.w = f2bf(r2.w);
    o3.x = f2bf(r3.x); o3.y = f2bf(r3.y); o3.z = f2bf(r3.z); o3.w = f2bf(r3.w);
    *(ushort4*)(dst)      = o0;
    *(ushort4*)(dst + 4)  = o1;
    *(ushort4*)(dst + 8)  = o2;
    *(ushort4*)(dst + 12) = o3;
}

// ---------------------------------------------------------------------------
// MFMA GEMM, 128x128 tile, BK=64, 4 waves (each 64x64 via 4x4 MFMA 16x16x32).
//  GATE: gate = sigmoid(A1@W1+A2@W2+bias); out = gate*gin1+(1-gate)*gin2
//  else: out = relu(A@W^T (+A2@W2^T) + bias)
// LDS staging swizzle: row r (128 B), slot s at pos p = s ^ (r&7).
// ---------------------------------------------------------------------------
struct GA {
    const unsigned short* A1; const unsigned short* W1;
    const unsigned short* A2; const unsigned short* W2;
    const float* bias;
    const unsigned short* gin1; const unsigned short* gin2;
    unsigned short* out;
};

template <bool DUAL, bool GATE>
__global__ __launch_bounds__(256) void mgemm_k(GA a0, GA a1) {
    GA g = (blockIdx.z == 0) ? a0 : a1;
    __shared__ __align__(16) unsigned short As[128 * 64];
    __shared__ __align__(16) unsigned short Bs[128 * 64];
    const int tid = threadIdx.x;
    const int lane = tid & 63;
    const int wave = tid >> 6;
    const int wr = wave & 1, wc = wave >> 1;
    const int bm = blockIdx.x * 128, bn = blockIdx.y * 128;

    f32x4 acc[4][4];
#pragma unroll
    for (int i = 0; i < 4; ++i)
#pragma unroll
        for (int j = 0; j < 4; ++j) {
            acc[i][j].x = 0.f; acc[i][j].y = 0.f; acc[i][j].z = 0.f; acc[i][j].w = 0.f;
        }

    // staging: entry e (16B) at LDS byte e*16; r=e>>3, pos=e&7 holds slot s=pos^(r&7)
    int rr[4], ss[4];
    unsigned short* dA[4];
    unsigned short* dB[4];
#pragma unroll
    for (int q = 0; q < 4; ++q) {
        int e = tid + 256 * q;
        rr[q] = e >> 3;
        ss[q] = (tid & 7) ^ (rr[q] & 7);
        dA[q] = As + (size_t)e * 8;     // e*16 bytes
        dB[q] = Bs + (size_t)e * 8;
    }

    // fragment LDS offsets (shorts): [micro-k t][frag i]
    int aoff[2][4], boff[2][4];
#pragma unroll
    for (int t = 0; t < 2; ++t)
#pragma unroll
        for (int i = 0; i < 4; ++i) {
            int sl = t * 4 + (lane >> 4);
            int p = sl ^ (lane & 7);
            int m = wr * 64 + i * 16 + (lane & 15);
            aoff[t][i] = m * 64 + p * 8;
            int n = wc * 64 + i * 16 + (lane & 15);
            boff[t][i] = n * 64 + p * 8;
        }

    const int nsrc = DUAL ? 2 : 1;
    for (int src = 0; src < nsrc; ++src) {
        const unsigned short* A = src ? g.A2 : g.A1;
        const unsigned short* W = src ? g.W2 : g.W1;
        const unsigned short* pa[4];
        const unsigned short* pb[4];
#pragma unroll
        for (int q = 0; q < 4; ++q) {
            pa[q] = A + (size_t)(bm + rr[q]) * DD + ss[q] * 8;
            pb[q] = W + (size_t)(bn + rr[q]) * DD + ss[q] * 8;
        }
        for (int k0 = 0; k0 < DD; k0 += 64) {
#pragma unroll
            for (int q = 0; q < 4; ++q) g2l16(pa[q] + k0, dA[q]);
#pragma unroll
            for (int q = 0; q < 4; ++q) g2l16(pb[q] + k0, dB[q]);
            __syncthreads();
            bf16x8 af[2][4], bf_[2][4];
#pragma unroll
            for (int t = 0; t < 2; ++t)
#pragma unroll
                for (int i = 0; i < 4; ++i) {
                    af[t][i]  = *(const bf16x8*)(As + aoff[t][i]);
                    bf_[t][i] = *(const bf16x8*)(Bs + boff[t][i]);
                }
#pragma unroll
            for (int t = 0; t < 2; ++t)
#pragma unroll
                for (int i = 0; i < 4; ++i)
#pragma unroll
                    for (int j = 0; j < 4; ++j)
                        acc[i][j] = __builtin_amdgcn_mfma_f32_16x16x32_bf16(
                            af[t][i], bf_[t][j], acc[i][j], 0, 0, 0);
            __syncthreads();
        }
    }

#pragma unroll
    for (int i = 0; i < 4; ++i) {
        int row = bm + wr * 64 + i * 16 + (lane >> 4) * 4;
#pragma unroll
        for (int j = 0; j < 4; ++j) {
            int col = bn + wc * 64 + j * 16 + (lane & 15);
            float bv = g.bias[col];
#pragma unroll
            for (int rg = 0; rg < 4; ++rg) {
                float v = acc[i][j][rg] + bv;
                size_t idx = (size_t)(row + rg) * DD + col;
                if (GATE) {
                    float gg = 1.f / (1.f + __expf(-v));
                    float x1 = bf2f(g.gin1[idx]);
                    float x2 = bf2f(g.gin2[idx]);
                    g.out[idx] = f2bf(gg * x1 + (1.f - gg) * x2);
                } else {
                    g.out[idx] = f2bf(fmaxf(v, 0.f));
                }
            }
        }
    }
}

// ---------------------------------------------------------------------------
// Outputs: gnn_info + partial max (y<16, vectorized float4) and
// num_embedding (y in [16,20), quarter per block)
// ---------------------------------------------------------------------------
__global__ __launch_bounds__(256) void gnn_k(const float* __restrict__ enc,
                                             const unsigned short* __restrict__ node,
                                             const int* __restrict__ slot,
                                             const float* __restrict__ num_enc,
                                             float* __restrict__ out_gnn,
                                             float* __restrict__ out_nemb,
                                             float* __restrict__ partial) {
    int b = blockIdx.x;
    int t = threadIdx.x;
    if (blockIdx.y >= 16) {
        int q = blockIdx.y - 16;
        size_t base = (size_t)b * NN * DD + (size_t)q * (NN * DD / 4);
        for (int it = 0; it < 4; ++it) {
            size_t i = base + (size_t)(it * 256 + t) * 4;
            float4 a = *(const float4*)(num_enc + i);
            ushort4 nb = *(const ushort4*)(node + i);
            float4 r;
            r.x = a.x + bf2f(nb.x);
            r.y = a.y + bf2f(nb.y);
            r.z = a.z + bf2f(nb.z);
            r.w = a.w + bf2f(nb.w);
            *(float4*)(out_nemb + i) = r;
        }
        return;
    }
    __shared__ int sl[32];
    __shared__ float4 red[128];
    int s0 = blockIdx.y * 32;
    if (t < 32) sl[t] = slot[b * SS + s0 + t];
    __syncthreads();
    const int dv = (t & 127) * 4;
    const int sh = t >> 7;
    float4 mx = {-INFINITY, -INFINITY, -INFINITY, -INFINITY};
#pragma unroll 4
    for (int i = 0; i < 16; ++i) {
        int sloc = sh * 16 + i;
        int s = s0 + sloc;
        int n = sl[sloc];
        size_t ebase = ((size_t)s * BB + b) * DD + dv;
        float4 v = *(const float4*)(enc + ebase);
        if (n >= 0) {
            ushort4 nb = *(const ushort4*)(node + ((size_t)b * NN + n) * DD + dv);
            v.x += bf2f(nb.x);
            v.y += bf2f(nb.y);
            v.z += bf2f(nb.z);
            v.w += bf2f(nb.w);
        }
        *(float4*)(out_gnn + ebase) = v;
        mx.x = fmaxf(mx.x, v.x);
        mx.y = fmaxf(mx.y, v.y);
        mx.z = fmaxf(mx.z, v.z);
        mx.w = fmaxf(mx.w, v.w);
    }
    if (sh == 1) red[t & 127] = mx;
    __syncthreads();
    if (sh == 0) {
        float4 o = red[t];
        mx.x = fmaxf(mx.x, o.x);
        mx.y = fmaxf(mx.y, o.y);
        mx.z = fmaxf(mx.z, o.z);
        mx.w = fmaxf(mx.w, o.w);
        *(float4*)(partial + ((size_t)b * 16 + blockIdx.y) * DD + dv) = mx;
    }
}

__global__ void pmax_k(const float* __restrict__ partial, float* __restrict__ out_prob) {
    int i = blockIdx.x * 256 + threadIdx.x;
    if (i >= BB * DD) return;
    int b = i >> 9, d = i & 511;
    float m = -INFINITY;
    for (int c = 0; c < 16; ++c) m = fmaxf(m, partial[((size_t)b * 16 + c) * DD + d]);
    out_prob[i] = m;
}

// ---------------------------------------------------------------------------
// Host launch
// ---------------------------------------------------------------------------
extern "C" void kernel_launch(void* const* d_in, const int* in_sizes, int n_in,
                              void* d_out, int out_size, void* d_ws, size_t ws_size,
                              hipStream_t stream) {
    const float* enc     = (const float*)d_in[0];
    const float* num_enc = (const float*)d_in[1];
    const int*   pos     = (const int*)d_in[2];
    const int*   order   = (const int*)d_in[3];
    const float* w_n1a = (const float*)d_in[4];  const float* b_n1a = (const float*)d_in[5];
    const float* w_n1b = (const float*)d_in[6];  const float* b_n1b = (const float*)d_in[7];
    const float* w_n2a = (const float*)d_in[8];  const float* b_n2a = (const float*)d_in[9];
    const float* w_n2b = (const float*)d_in[10]; const float* b_n2b = (const float*)d_in[11];
    const float* w_g   = (const float*)d_in[12]; const float* b_g   = (const float*)d_in[13];
    const float* w_o   = (const float*)d_in[14]; const float* b_o   = (const float*)d_in[15];

    char* wp = (char*)d_ws;
    float* g_gt = (float*)wp;        wp += (size_t)BB * NN * NN * 4;
    float* g_lt = (float*)wp;        wp += (size_t)BB * NN * NN * 4;
    float* partial = (float*)wp;     wp += (size_t)BB * 16 * DD * 4;
    int* slot = (int*)wp;            wp += (size_t)BB * SS * 4;
    unsigned short* Wt = (unsigned short*)wp;    wp += (size_t)16 * DSQ * 2;
    unsigned short* node0 = (unsigned short*)wp; wp += (size_t)MM * DD * 2;
    unsigned short* nodeA = (unsigned short*)wp; wp += (size_t)MM * DD * 2;
    unsigned short* nodeB = (unsigned short*)wp; wp += (size_t)MM * DD * 2;
    unsigned short* ni1 = (unsigned short*)wp;   wp += (size_t)MM * DD * 2;
    unsigned short* ni2 = (unsigned short*)wp;   wp += (size_t)MM * DD * 2;
    unsigned short* t1 = (unsigned short*)wp;    wp += (size_t)MM * DD * 2;
    unsigned short* t2 = (unsigned short*)wp;    wp += (size_t)MM * DD * 2;

    float* out_gnn  = (float*)d_out;
    float* out_nemb = out_gnn + (size_t)SS * BB * DD;
    float* out_prob = out_nemb + (size_t)BB * NN * DD;

    // Setup (3 dispatches)
    adj_k<<<BB, 256, 0, stream>>>(order, pos, g_gt, g_lt, slot);

    WSfull wsrc;
    const float* srcs[12] = {w_n1a, w_n1b, w_n2a, w_n2b, w_o, w_o + DSQ,
                             w_n1a + DSQ, w_n1b + DSQ, w_n2a + DSQ, w_n2b + DSQ,
                             w_o + 2 * DSQ, w_o + 3 * DSQ};
    int slots[12] = {0, 1, 2, 3, 6, 7, 8, 9, 10, 11, 14, 15};
    for (int i = 0; i < 12; ++i) { wsrc.s[i] = srcs[i]; wsrc.slot[i] = slots[i]; }
    wsrc.w_g = w_g;
    wprep_k<<<dim3(14, 64), 256, 0, stream>>>(wsrc, Wt);
    conv_k<<<(MM * DD) / 1024, 256, 0, stream>>>(num_enc, node0);

    dim3 ggrid(32, 4, 2);   // stage GEMMs: two GEMMs per dispatch
    dim3 sgrid(32, 4, 1);   // DUAL GEMMs
    dim3 mgrid(BB, 4, 2);   // mix

    const unsigned short* nodeIn = node0;
    for (int h = 0; h < HH; ++h) {
        unsigned short* nodeOut = (h == 0) ? nodeA : nodeB;
        unsigned short* zb1 = (h == 0) ? nodeB : node0;       // free node buffer
        unsigned short* zb2 = (unsigned short*)partial;       // scratch reuse (4 MB)
        const unsigned short* Wh = Wt + (size_t)h * 8 * DSQ;

        // mix A: t1 = g_gt@x ; t2 = g_lt@x
        mix_k<<<mgrid, 256, 0, stream>>>(g_gt, g_lt, nodeIn, nodeIn, t1, t2);
        // stage A: ni1 = relu(t1@W1a+b); ni2 = relu(t2@W2a+b)
        GA sa0 = {t1, Wh + 0 * DSQ, nullptr, nullptr, b_n1a + h * DD, nullptr, nullptr, ni1};
        GA sa1 = {t2, Wh + 2 * DSQ, nullptr, nullptr, b_n2a + h * DD, nullptr, nullptr, ni2};
        mgemm_k<false, false><<<ggrid, 256, 0, stream>>>(sa0, sa1);

        // mix B: zb1 = g_gt@ni1 ; zb2 = g_lt@ni2
        mix_k<<<mgrid, 256, 0, stream>>>(g_gt, g_lt, ni1, ni2, zb1, zb2);
        // stage B: t1 = relu(zb1@W1b+b); t2 = relu(zb2@W2b+b)
        GA sb0 = {zb1, Wh + 1 * DSQ, nullptr, nullptr, b_n1b + h * DD, nullptr, nullptr, t1};
        GA sb1 = {zb2, Wh + 3 * DSQ, nullptr, nullptr, b_n2b + h * DD, nullptr, nullptr, t2};
        mgemm_k<false, false><<<ggrid, 256, 0, stream>>>(sb0, sb1);

        // gate: info = gate*t1 + (1-gate)*t2  -> ni1
        GA gg = {t1, Wh + 4 * DSQ, t2, Wh + 5 * DSQ, b_g + h * DD, t1, t2, ni1};
        mgemm_k<true, true><<<sgrid, 256, 0, stream>>>(gg, gg);

        // out: node = relu(x@Wo_a + info@Wo_b + b)
        GA go = {nodeIn, Wh + 6 * DSQ, ni1, Wh + 7 * DSQ, b_o + h * DD,
                 nullptr, nullptr, nodeOut};
        mgemm_k<true, false><<<sgrid, 256, 0, stream>>>(go, go);

        nodeIn = nodeOut;
    }
    const unsigned short* nodeF = nodeIn;

    // Outputs (2 dispatches)
    gnn_k<<<dim3(BB, 20), 256, 0, stream>>>(enc, nodeF, slot, num_enc,
                                            out_gnn, out_nemb, partial);
    pmax_k<<<(BB * DD) / 256, 256, 0, stream>>>(partial, out_prob);
}

// Round 3
// 447.830 us; speedup vs baseline: 1.0595x; 1.0595x over previous
//
#include <hip/hip_runtime.h>
#include <math.h>

// Problem constants
#define BB 128
#define SS 512
#define NN 32
#define DD 512
#define HH 2
#define MM (BB * NN)          // 4096 rows
#define DSQ (DD * DD)         // 262144

typedef short bf16x8 __attribute__((ext_vector_type(8)));
typedef float f32x4 __attribute__((ext_vector_type(4)));

__device__ __forceinline__ unsigned short f2bf(float f) {
    unsigned int u = __float_as_uint(f);
    u += 0x7fffu + ((u >> 16) & 1u);
    return (unsigned short)(u >> 16);
}
__device__ __forceinline__ float bf2f(unsigned short h) {
    return __uint_as_float(((unsigned int)h) << 16);
}
__device__ __forceinline__ void g2l16(const void* gp, void* lp) {
    __builtin_amdgcn_global_load_lds(
        (const __attribute__((address_space(1))) void*)gp,
        (__attribute__((address_space(3))) void*)lp, 16, 0, 0);
}

// ---------------------------------------------------------------------------
// adj + slot map fused: g_gt/g_lt [B,32,32] row-normalized; slot[b][s]
// ---------------------------------------------------------------------------
__global__ __launch_bounds__(256) void adj_k(const int* __restrict__ order,
                                             const int* __restrict__ pos,
                                             float* __restrict__ g_gt,
                                             float* __restrict__ g_lt,
                                             int* __restrict__ slot) {
    int b = blockIdx.x;
    __shared__ int ord[NN];
    __shared__ float sgt[NN][NN + 1];
    __shared__ float slt[NN][NN + 1];
    __shared__ float rs_gt[NN], rs_lt[NN];
    int tid = threadIdx.x;
    slot[b * SS + tid] = -1;
    slot[b * SS + 256 + tid] = -1;
    if (tid < NN) ord[tid] = order[b * NN + tid];
    __syncthreads();
    for (int q = 0; q < 4; ++q) {
        int idx = tid + 256 * q;
        int n = idx >> 5, m = idx & 31;
        bool valid = (ord[n] > 0) && (ord[m] > 0) && (n != m);
        float eye = (n == m) ? 1.f : 0.f;
        bool gt = ord[n] > ord[m];
        sgt[n][m] = ((valid && gt) ? 1.f : 0.f) + eye;
        slt[n][m] = ((valid && !gt) ? 1.f : 0.f) + eye;
    }
    __syncthreads();
    if (tid < NN) {
        float s1 = 0.f, s2 = 0.f;
        for (int m = 0; m < NN; ++m) { s1 += sgt[tid][m]; s2 += slt[tid][m]; }
        rs_gt[tid] = s1; rs_lt[tid] = s2;
    }
    __syncthreads();
    for (int q = 0; q < 4; ++q) {
        int idx = tid + 256 * q;
        int n = idx >> 5, m = idx & 31;
        g_gt[b * 1024 + idx] = sgt[n][m] / rs_gt[n];
        g_lt[b * 1024 + idx] = slt[n][m] / rs_lt[n];
    }
    if (tid < NN) {
        int p = pos[b * NN + tid];
        if (p >= 0) slot[b * SS + p] = tid;
    }
}

// ---------------------------------------------------------------------------
// Weight prep (transpose + bf16) + gate-weight combine, one kernel.
// ---------------------------------------------------------------------------
struct WSfull { const float* s[12]; int slot[12]; const float* w_g; };

__global__ __launch_bounds__(256) void wprep_k(WSfull w, unsigned short* __restrict__ Wt) {
    int which = blockIdx.x;
    int tile = blockIdx.y;
    int tr = (tile >> 3) * 64, tc = (tile & 7) * 64;
    __shared__ float c1[64][65];
    __shared__ float c2[64][65];
    int lc = threadIdx.x & 63, g4 = threadIdx.x >> 6;
    if (which < 12) {
        const float* src = w.s[which];
        unsigned short* dst = Wt + (size_t)w.slot[which] * DSQ;
        for (int i = 0; i < 16; ++i) {
            int lr = g4 * 16 + i;
            c1[lr][lc] = src[(size_t)(tr + lr) * DD + tc + lc];
        }
        __syncthreads();
        for (int i = 0; i < 16; ++i) {
            int lr = g4 * 16 + i;
            dst[(size_t)(tc + lr) * DD + tr + lc] = f2bf(c1[lc][lr]);
        }
    } else {
        int h = which - 12;
        const float* base = w.w_g + (size_t)h * 4 * DSQ;
        for (int i = 0; i < 16; ++i) {
            int lr = g4 * 16 + i;
            int k = tr + lr, n = tc + lc;
            float a  = base[(size_t)k * DD + n];
            float b2 = base[(size_t)(DD + k) * DD + n];
            float c  = base[(size_t)(2 * DD + k) * DD + n];
            float d4 = base[(size_t)(3 * DD + k) * DD + n];
            c1[lr][lc] = a + c + d4;
            c2[lr][lc] = b2 + c - d4;
        }
        __syncthreads();
        unsigned short* d1 = Wt + (size_t)(h * 8 + 4) * DSQ;
        unsigned short* d2 = Wt + (size_t)(h * 8 + 5) * DSQ;
        for (int i = 0; i < 16; ++i) {
            int lr = g4 * 16 + i;
            d1[(size_t)(tc + lr) * DD + tr + lc] = f2bf(c1[lc][lr]);
            d2[(size_t)(tc + lr) * DD + tr + lc] = f2bf(c2[lc][lr]);
        }
    }
}

// fp32 -> bf16 conversion (num_enc -> node0)
__global__ void conv_k(const float* __restrict__ x, unsigned short* __restrict__ o) {
    size_t i = ((size_t)blockIdx.x * 256 + threadIdx.x) * 4;
    float4 v = *(const float4*)(x + i);
    ushort4 r;
    r.x = f2bf(v.x); r.y = f2bf(v.y); r.z = f2bf(v.z); r.w = f2bf(v.w);
    *(ushort4*)(o + i) = r;
}

// ---------------------------------------------------------------------------
// mix_k: Z[b*32+n, :] = sum_m G[b,n,m] * X[b*32+m, :]   (fp32 accum, bf16 out)
// grid (BB, DD/128, 2): z=0 -> (g_gt, X1, Z1); z=1 -> (g_lt, X2, Z2)
// ---------------------------------------------------------------------------
__global__ __launch_bounds__(256) void mix_k(const float* __restrict__ g_gt,
                                             const float* __restrict__ g_lt,
                                             const unsigned short* __restrict__ X1,
                                             const unsigned short* __restrict__ X2,
                                             unsigned short* __restrict__ Z1,
                                             unsigned short* __restrict__ Z2) {
    const int b = blockIdx.x;
    const int dc = blockIdx.y * 128;
    const float* G = blockIdx.z ? g_lt : g_gt;
    const unsigned short* X = blockIdx.z ? X2 : X1;
    unsigned short* Z = blockIdx.z ? Z2 : Z1;
    __shared__ float gs[NN * 33];        // padded stride 33 -> conflict-free
    __shared__ float xs[NN][128];
    const int t = threadIdx.x;
    {
        float4 v = ((const float4*)(G + (size_t)b * 1024))[t];
        int n = t >> 3, m0 = (t & 7) * 4;
        float* gp = gs + n * 33 + m0;
        gp[0] = v.x; gp[1] = v.y; gp[2] = v.z; gp[3] = v.w;
    }
#pragma unroll
    for (int q = 0; q < 2; ++q) {
        int e = t + 256 * q;
        int m = e >> 4, c = (e & 15) * 8;
        const unsigned short* src = X + ((size_t)(b * NN + m)) * DD + dc + c;
        ushort4 lo = *(const ushort4*)src;
        ushort4 hi = *(const ushort4*)(src + 4);
        float* xp = &xs[m][c];
        xp[0] = bf2f(lo.x); xp[1] = bf2f(lo.y); xp[2] = bf2f(lo.z); xp[3] = bf2f(lo.w);
        xp[4] = bf2f(hi.x); xp[5] = bf2f(hi.y); xp[6] = bf2f(hi.z); xp[7] = bf2f(hi.w);
    }
    __syncthreads();
    const int n = t >> 3;
    const int c0 = (t & 7) * 16;
    f32x4 r0 = {0.f, 0.f, 0.f, 0.f}, r1 = r0, r2 = r0, r3 = r0;
#pragma unroll
    for (int m = 0; m < NN; ++m) {
        float gv = gs[n * 33 + m];
        const float* xr = &xs[m][c0];
        r0 += gv * *(const f32x4*)(xr);
        r1 += gv * *(const f32x4*)(xr + 4);
        r2 += gv * *(const f32x4*)(xr + 8);
        r3 += gv * *(const f32x4*)(xr + 12);
    }
    unsigned short* dst = Z + ((size_t)(b * NN + n)) * DD + dc + c0;
    ushort4 o0, o1, o2, o3;
    o0.x = f2bf(r0.x); o0.y = f2bf(r0.y); o0.z = f2bf(r0.z); o0.w = f2bf(r0.w);
    o1.x = f2bf(r1.x); o1.y = f2bf(r1.y); o1.z = f2bf(r1.z); o1.w = f2bf(r1.w);
    o2.x = f2bf(r2.x); o2.y = f2bf(r2.y); o2.z = f2bf(r2.z); o2.w = f2bf(r2.w);
    o3.x = f2bf(r3.x); o3.y = f2bf(r3.y); o3.z = f2bf(r3.z); o3.w = f2bf(r3.w);
    *(ushort4*)(dst)      = o0;
    *(ushort4*)(dst + 4)  = o1;
    *(ushort4*)(dst + 8)  = o2;
    *(ushort4*)(dst + 12) = o3;
}

// ---------------------------------------------------------------------------
// MFMA GEMM, 64x128 tile, BK=64, 4 waves (each 32x64 via 2x4 MFMA 16x16x32).
//  GATE: gate = sigmoid(A1@W1+A2@W2+bias); out = gate*gin1+(1-gate)*gin2
//  else: out = relu(A@W^T (+A2@W2^T) + bias)
// LDS staging swizzle: row r (128 B), slot s at pos p = s ^ (r&7).
// Grid: (M/64, DD/128, nGemm) -> 512 blocks for stage pairs = 2 blocks/CU.
// ---------------------------------------------------------------------------
struct GA {
    const unsigned short* A1; const unsigned short* W1;
    const unsigned short* A2; const unsigned short* W2;
    const float* bias;
    const unsigned short* gin1; const unsigned short* gin2;
    unsigned short* out;
};

template <bool DUAL, bool GATE>
__global__ __launch_bounds__(256) void mgemm_k(GA a0, GA a1) {
    GA g = (blockIdx.z == 0) ? a0 : a1;
    __shared__ __align__(16) unsigned short As[64 * 64];    //  8 KB
    __shared__ __align__(16) unsigned short Bs[128 * 64];   // 16 KB
    const int tid = threadIdx.x;
    const int lane = tid & 63;
    const int wave = tid >> 6;
    const int wr = wave & 1, wc = wave >> 1;
    const int bm = blockIdx.x * 64, bn = blockIdx.y * 128;

    f32x4 acc[2][4];
#pragma unroll
    for (int i = 0; i < 2; ++i)
#pragma unroll
        for (int j = 0; j < 4; ++j) {
            acc[i][j].x = 0.f; acc[i][j].y = 0.f; acc[i][j].z = 0.f; acc[i][j].w = 0.f;
        }

    // staging: entry e (16B) at LDS byte e*16; r=e>>3, pos=e&7 holds slot s=pos^(r&7)
    int rA[2], sA[2], rB[4], sB[4];
    unsigned short *dA[2], *dB[4];
#pragma unroll
    for (int q = 0; q < 2; ++q) {
        int e = tid + 256 * q;
        rA[q] = e >> 3;
        sA[q] = (tid & 7) ^ (rA[q] & 7);
        dA[q] = As + (size_t)e * 8;
    }
#pragma unroll
    for (int q = 0; q < 4; ++q) {
        int e = tid + 256 * q;
        rB[q] = e >> 3;
        sB[q] = (tid & 7) ^ (rB[q] & 7);
        dB[q] = Bs + (size_t)e * 8;
    }

    // fragment LDS offsets (shorts): [micro-k t][frag]
    int aoff[2][2], boff[2][4];
#pragma unroll
    for (int t = 0; t < 2; ++t) {
        int sl = t * 4 + (lane >> 4);
        int p = sl ^ (lane & 7);
#pragma unroll
        for (int i = 0; i < 2; ++i) {
            int m = wr * 32 + i * 16 + (lane & 15);
            aoff[t][i] = m * 64 + p * 8;
        }
#pragma unroll
        for (int j = 0; j < 4; ++j) {
            int n = wc * 64 + j * 16 + (lane & 15);
            boff[t][j] = n * 64 + p * 8;
        }
    }

    const int nsrc = DUAL ? 2 : 1;
    for (int src = 0; src < nsrc; ++src) {
        const unsigned short* A = src ? g.A2 : g.A1;
        const unsigned short* W = src ? g.W2 : g.W1;
        const unsigned short* pa[2];
        const unsigned short* pb[4];
#pragma unroll
        for (int q = 0; q < 2; ++q) pa[q] = A + (size_t)(bm + rA[q]) * DD + sA[q] * 8;
#pragma unroll
        for (int q = 0; q < 4; ++q) pb[q] = W + (size_t)(bn + rB[q]) * DD + sB[q] * 8;
        for (int k0 = 0; k0 < DD; k0 += 64) {
#pragma unroll
            for (int q = 0; q < 2; ++q) g2l16(pa[q] + k0, dA[q]);
#pragma unroll
            for (int q = 0; q < 4; ++q) g2l16(pb[q] + k0, dB[q]);
            __syncthreads();
            bf16x8 af[2][2], bf_[2][4];
#pragma unroll
            for (int t = 0; t < 2; ++t) {
#pragma unroll
                for (int i = 0; i < 2; ++i) af[t][i] = *(const bf16x8*)(As + aoff[t][i]);
#pragma unroll
                for (int j = 0; j < 4; ++j) bf_[t][j] = *(const bf16x8*)(Bs + boff[t][j]);
            }
#pragma unroll
            for (int t = 0; t < 2; ++t)
#pragma unroll
                for (int i = 0; i < 2; ++i)
#pragma unroll
                    for (int j = 0; j < 4; ++j)
                        acc[i][j] = __builtin_amdgcn_mfma_f32_16x16x32_bf16(
                            af[t][i], bf_[t][j], acc[i][j], 0, 0, 0);
            __syncthreads();
        }
    }

#pragma unroll
    for (int i = 0; i < 2; ++i) {
        int row = bm + wr * 32 + i * 16 + (lane >> 4) * 4;
#pragma unroll
        for (int j = 0; j < 4; ++j) {
            int col = bn + wc * 64 + j * 16 + (lane & 15);
            float bv = g.bias[col];
#pragma unroll
            for (int rg = 0; rg < 4; ++rg) {
                float v = acc[i][j][rg] + bv;
                size_t idx = (size_t)(row + rg) * DD + col;
                if (GATE) {
                    float gg = 1.f / (1.f + __expf(-v));
                    float x1 = bf2f(g.gin1[idx]);
                    float x2 = bf2f(g.gin2[idx]);
                    g.out[idx] = f2bf(gg * x1 + (1.f - gg) * x2);
                } else {
                    g.out[idx] = f2bf(fmaxf(v, 0.f));
                }
            }
        }
    }
}

// ---------------------------------------------------------------------------
// Outputs: gnn_info + partial max (y<16, vectorized float4) and
// num_embedding (y in [16,20), quarter per block)
// ---------------------------------------------------------------------------
__global__ __launch_bounds__(256) void gnn_k(const float* __restrict__ enc,
                                             const unsigned short* __restrict__ node,
                                             const int* __restrict__ slot,
                                             const float* __restrict__ num_enc,
                                             float* __restrict__ out_gnn,
                                             float* __restrict__ out_nemb,
                                             float* __restrict__ partial) {
    int b = blockIdx.x;
    int t = threadIdx.x;
    if (blockIdx.y >= 16) {
        int q = blockIdx.y - 16;
        size_t base = (size_t)b * NN * DD + (size_t)q * (NN * DD / 4);
        for (int it = 0; it < 4; ++it) {
            size_t i = base + (size_t)(it * 256 + t) * 4;
            float4 a = *(const float4*)(num_enc + i);
            ushort4 nb = *(const ushort4*)(node + i);
            float4 r;
            r.x = a.x + bf2f(nb.x);
            r.y = a.y + bf2f(nb.y);
            r.z = a.z + bf2f(nb.z);
            r.w = a.w + bf2f(nb.w);
            *(float4*)(out_nemb + i) = r;
        }
        return;
    }
    __shared__ int sl[32];
    __shared__ float4 red[128];
    int s0 = blockIdx.y * 32;
    if (t < 32) sl[t] = slot[b * SS + s0 + t];
    __syncthreads();
    const int dv = (t & 127) * 4;
    const int sh = t >> 7;
    float4 mx = {-INFINITY, -INFINITY, -INFINITY, -INFINITY};
#pragma unroll 4
    for (int i = 0; i < 16; ++i) {
        int sloc = sh * 16 + i;
        int s = s0 + sloc;
        int n = sl[sloc];
        size_t ebase = ((size_t)s * BB + b) * DD + dv;
        float4 v = *(const float4*)(enc + ebase);
        if (n >= 0) {
            ushort4 nb = *(const ushort4*)(node + ((size_t)b * NN + n) * DD + dv);
            v.x += bf2f(nb.x);
            v.y += bf2f(nb.y);
            v.z += bf2f(nb.z);
            v.w += bf2f(nb.w);
        }
        *(float4*)(out_gnn + ebase) = v;
        mx.x = fmaxf(mx.x, v.x);
        mx.y = fmaxf(mx.y, v.y);
        mx.z = fmaxf(mx.z, v.z);
        mx.w = fmaxf(mx.w, v.w);
    }
    if (sh == 1) red[t & 127] = mx;
    __syncthreads();
    if (sh == 0) {
        float4 o = red[t];
        mx.x = fmaxf(mx.x, o.x);
        mx.y = fmaxf(mx.y, o.y);
        mx.z = fmaxf(mx.z, o.z);
        mx.w = fmaxf(mx.w, o.w);
        *(float4*)(partial + ((size_t)b * 16 + blockIdx.y) * DD + dv) = mx;
    }
}

__global__ void pmax_k(const float* __restrict__ partial, float* __restrict__ out_prob) {
    int i = blockIdx.x * 256 + threadIdx.x;
    if (i >= BB * DD) return;
    int b = i >> 9, d = i & 511;
    float m = -INFINITY;
    for (int c = 0; c < 16; ++c) m = fmaxf(m, partial[((size_t)b * 16 + c) * DD + d]);
    out_prob[i] = m;
}

// ---------------------------------------------------------------------------
// Host launch
// ---------------------------------------------------------------------------
extern "C" void kernel_launch(void* const* d_in, const int* in_sizes, int n_in,
                              void* d_out, int out_size, void* d_ws, size_t ws_size,
                              hipStream_t stream) {
    const float* enc     = (const float*)d_in[0];
    const float* num_enc = (const float*)d_in[1];
    const int*   pos     = (const int*)d_in[2];
    const int*   order   = (const int*)d_in[3];
    const float* w_n1a = (const float*)d_in[4];  const float* b_n1a = (const float*)d_in[5];
    const float* w_n1b = (const float*)d_in[6];  const float* b_n1b = (const float*)d_in[7];
    const float* w_n2a = (const float*)d_in[8];  const float* b_n2a = (const float*)d_in[9];
    const float* w_n2b = (const float*)d_in[10]; const float* b_n2b = (const float*)d_in[11];
    const float* w_g   = (const float*)d_in[12]; const float* b_g   = (const float*)d_in[13];
    const float* w_o   = (const float*)d_in[14]; const float* b_o   = (const float*)d_in[15];

    char* wp = (char*)d_ws;
    float* g_gt = (float*)wp;        wp += (size_t)BB * NN * NN * 4;
    float* g_lt = (float*)wp;        wp += (size_t)BB * NN * NN * 4;
    float* partial = (float*)wp;     wp += (size_t)BB * 16 * DD * 4;
    int* slot = (int*)wp;            wp += (size_t)BB * SS * 4;
    unsigned short* Wt = (unsigned short*)wp;    wp += (size_t)16 * DSQ * 2;
    unsigned short* node0 = (unsigned short*)wp; wp += (size_t)MM * DD * 2;
    unsigned short* nodeA = (unsigned short*)wp; wp += (size_t)MM * DD * 2;
    unsigned short* nodeB = (unsigned short*)wp; wp += (size_t)MM * DD * 2;
    unsigned short* ni1 = (unsigned short*)wp;   wp += (size_t)MM * DD * 2;
    unsigned short* ni2 = (unsigned short*)wp;   wp += (size_t)MM * DD * 2;
    unsigned short* t1 = (unsigned short*)wp;    wp += (size_t)MM * DD * 2;
    unsigned short* t2 = (unsigned short*)wp;    wp += (size_t)MM * DD * 2;

    float* out_gnn  = (float*)d_out;
    float* out_nemb = out_gnn + (size_t)SS * BB * DD;
    float* out_prob = out_nemb + (size_t)BB * NN * DD;

    // Setup (3 dispatches)
    adj_k<<<BB, 256, 0, stream>>>(order, pos, g_gt, g_lt, slot);

    WSfull wsrc;
    const float* srcs[12] = {w_n1a, w_n1b, w_n2a, w_n2b, w_o, w_o + DSQ,
                             w_n1a + DSQ, w_n1b + DSQ, w_n2a + DSQ, w_n2b + DSQ,
                             w_o + 2 * DSQ, w_o + 3 * DSQ};
    int slots[12] = {0, 1, 2, 3, 6, 7, 8, 9, 10, 11, 14, 15};
    for (int i = 0; i < 12; ++i) { wsrc.s[i] = srcs[i]; wsrc.slot[i] = slots[i]; }
    wsrc.w_g = w_g;
    wprep_k<<<dim3(14, 64), 256, 0, stream>>>(wsrc, Wt);
    conv_k<<<(MM * DD) / 1024, 256, 0, stream>>>(num_enc, node0);

    dim3 ggrid(MM / 64, DD / 128, 2);   // stage GEMMs: 64x4x2 = 512 blocks
    dim3 sgrid(MM / 64, DD / 128, 1);   // DUAL GEMMs:  64x4   = 256 blocks
    dim3 mgrid(BB, 4, 2);               // mix

    const unsigned short* nodeIn = node0;
    for (int h = 0; h < HH; ++h) {
        unsigned short* nodeOut = (h == 0) ? nodeA : nodeB;
        unsigned short* zb1 = (h == 0) ? nodeB : node0;       // free node buffer
        unsigned short* zb2 = (unsigned short*)partial;       // scratch reuse (4 MB)
        const unsigned short* Wh = Wt + (size_t)h * 8 * DSQ;

        // mix A: t1 = g_gt@x ; t2 = g_lt@x
        mix_k<<<mgrid, 256, 0, stream>>>(g_gt, g_lt, nodeIn, nodeIn, t1, t2);
        // stage A: ni1 = relu(t1@W1a+b); ni2 = relu(t2@W2a+b)
        GA sa0 = {t1, Wh + 0 * DSQ, nullptr, nullptr, b_n1a + h * DD, nullptr, nullptr, ni1};
        GA sa1 = {t2, Wh + 2 * DSQ, nullptr, nullptr, b_n2a + h * DD, nullptr, nullptr, ni2};
        mgemm_k<false, false><<<ggrid, 256, 0, stream>>>(sa0, sa1);

        // mix B: zb1 = g_gt@ni1 ; zb2 = g_lt@ni2
        mix_k<<<mgrid, 256, 0, stream>>>(g_gt, g_lt, ni1, ni2, zb1, zb2);
        // stage B: t1 = relu(zb1@W1b+b); t2 = relu(zb2@W2b+b)
        GA sb0 = {zb1, Wh + 1 * DSQ, nullptr, nullptr, b_n1b + h * DD, nullptr, nullptr, t1};
        GA sb1 = {zb2, Wh + 3 * DSQ, nullptr, nullptr, b_n2b + h * DD, nullptr, nullptr, t2};
        mgemm_k<false, false><<<ggrid, 256, 0, stream>>>(sb0, sb1);

        // gate: info = gate*t1 + (1-gate)*t2  -> ni1
        GA gg = {t1, Wh + 4 * DSQ, t2, Wh + 5 * DSQ, b_g + h * DD, t1, t2, ni1};
        mgemm_k<true, true><<<sgrid, 256, 0, stream>>>(gg, gg);

        // out: node = relu(x@Wo_a + info@Wo_b + b)
        GA go = {nodeIn, Wh + 6 * DSQ, ni1, Wh + 7 * DSQ, b_o + h * DD,
                 nullptr, nullptr, nodeOut};
        mgemm_k<true, false><<<sgrid, 256, 0, stream>>>(go, go);

        nodeIn = nodeOut;
    }
    const unsigned short* nodeF = nodeIn;

    // Outputs (2 dispatches)
    gnn_k<<<dim3(BB, 20), 256, 0, stream>>>(enc, nodeF, slot, num_enc,
                                            out_gnn, out_nemb, partial);
    pmax_k<<<(BB * DD) / 256, 256, 0, stream>>>(partial, out_prob);
}

// Round 6
// 423.785 us; speedup vs baseline: 1.1196x; 1.0567x over previous
//
#include <hip/hip_runtime.h>
#include <math.h>

// Problem constants
#define BB 128
#define SS 512
#define NN 32
#define DD 512
#define HH 2
#define MM (BB * NN)          // 4096 rows
#define DSQ (DD * DD)         // 262144

typedef short bf16x8 __attribute__((ext_vector_type(8)));
typedef float f32x4 __attribute__((ext_vector_type(4)));

__device__ __forceinline__ unsigned short f2bf(float f) {
    unsigned int u = __float_as_uint(f);
    u += 0x7fffu + ((u >> 16) & 1u);
    return (unsigned short)(u >> 16);
}
__device__ __forceinline__ float bf2f(unsigned short h) {
    return __uint_as_float(((unsigned int)h) << 16);
}
__device__ __forceinline__ void g2l16(const void* gp, void* lp) {
    __builtin_amdgcn_global_load_lds(
        (const __attribute__((address_space(1))) void*)gp,
        (__attribute__((address_space(3))) void*)lp, 16, 0, 0);
}

// ---------------------------------------------------------------------------
// adj + slot map fused: g_gt/g_lt [B,32,32] row-normalized; slot[b][s]
// ---------------------------------------------------------------------------
__global__ __launch_bounds__(256) void adj_k(const int* __restrict__ order,
                                             const int* __restrict__ pos,
                                             float* __restrict__ g_gt,
                                             float* __restrict__ g_lt,
                                             int* __restrict__ slot) {
    int b = blockIdx.x;
    __shared__ int ord[NN];
    __shared__ float sgt[NN][NN + 1];
    __shared__ float slt[NN][NN + 1];
    __shared__ float rs_gt[NN], rs_lt[NN];
    int tid = threadIdx.x;
    slot[b * SS + tid] = -1;
    slot[b * SS + 256 + tid] = -1;
    if (tid < NN) ord[tid] = order[b * NN + tid];
    __syncthreads();
    for (int q = 0; q < 4; ++q) {
        int idx = tid + 256 * q;
        int n = idx >> 5, m = idx & 31;
        bool valid = (ord[n] > 0) && (ord[m] > 0) && (n != m);
        float eye = (n == m) ? 1.f : 0.f;
        bool gt = ord[n] > ord[m];
        sgt[n][m] = ((valid && gt) ? 1.f : 0.f) + eye;
        slt[n][m] = ((valid && !gt) ? 1.f : 0.f) + eye;
    }
    __syncthreads();
    if (tid < NN) {
        float s1 = 0.f, s2 = 0.f;
        for (int m = 0; m < NN; ++m) { s1 += sgt[tid][m]; s2 += slt[tid][m]; }
        rs_gt[tid] = s1; rs_lt[tid] = s2;
    }
    __syncthreads();
    for (int q = 0; q < 4; ++q) {
        int idx = tid + 256 * q;
        int n = idx >> 5, m = idx & 31;
        g_gt[b * 1024 + idx] = sgt[n][m] / rs_gt[n];
        g_lt[b * 1024 + idx] = slt[n][m] / rs_lt[n];
    }
    if (tid < NN) {
        int p = pos[b * NN + tid];
        if (p >= 0) slot[b * SS + p] = tid;
    }
}

// ---------------------------------------------------------------------------
// Weight prep (transpose + bf16) + gate-weight combine, one kernel.
// ---------------------------------------------------------------------------
struct WSfull { const float* s[12]; int slot[12]; const float* w_g; };

__global__ __launch_bounds__(256) void wprep_k(WSfull w, unsigned short* __restrict__ Wt) {
    int which = blockIdx.x;
    int tile = blockIdx.y;
    int tr = (tile >> 3) * 64, tc = (tile & 7) * 64;
    __shared__ float c1[64][65];
    __shared__ float c2[64][65];
    int lc = threadIdx.x & 63, g4 = threadIdx.x >> 6;
    if (which < 12) {
        const float* src = w.s[which];
        unsigned short* dst = Wt + (size_t)w.slot[which] * DSQ;
        for (int i = 0; i < 16; ++i) {
            int lr = g4 * 16 + i;
            c1[lr][lc] = src[(size_t)(tr + lr) * DD + tc + lc];
        }
        __syncthreads();
        for (int i = 0; i < 16; ++i) {
            int lr = g4 * 16 + i;
            dst[(size_t)(tc + lr) * DD + tr + lc] = f2bf(c1[lc][lr]);
        }
    } else {
        int h = which - 12;
        const float* base = w.w_g + (size_t)h * 4 * DSQ;
        for (int i = 0; i < 16; ++i) {
            int lr = g4 * 16 + i;
            int k = tr + lr, n = tc + lc;
            float a  = base[(size_t)k * DD + n];
            float b2 = base[(size_t)(DD + k) * DD + n];
            float c  = base[(size_t)(2 * DD + k) * DD + n];
            float d4 = base[(size_t)(3 * DD + k) * DD + n];
            c1[lr][lc] = a + c + d4;
            c2[lr][lc] = b2 + c - d4;
        }
        __syncthreads();
        unsigned short* d1 = Wt + (size_t)(h * 8 + 4) * DSQ;
        unsigned short* d2 = Wt + (size_t)(h * 8 + 5) * DSQ;
        for (int i = 0; i < 16; ++i) {
            int lr = g4 * 16 + i;
            d1[(size_t)(tc + lr) * DD + tr + lc] = f2bf(c1[lc][lr]);
            d2[(size_t)(tc + lr) * DD + tr + lc] = f2bf(c2[lc][lr]);
        }
    }
}

// ---------------------------------------------------------------------------
// convmix_k: node0 = bf16(num_enc); t1 = bf16(g_gt@num_enc); t2 = bf16(g_lt@num_enc)
// grid (BB, DD/128)
// ---------------------------------------------------------------------------
__global__ __launch_bounds__(256) void convmix_k(const float* __restrict__ x,
                                                 const float* __restrict__ g_gt,
                                                 const float* __restrict__ g_lt,
                                                 unsigned short* __restrict__ node0,
                                                 unsigned short* __restrict__ t1,
                                                 unsigned short* __restrict__ t2) {
    const int b = blockIdx.x;
    const int dc = blockIdx.y * 128;
    __shared__ float xs[NN][128];      // 16 KB
    __shared__ float gg[2][NN][NN];    // 8 KB
    const int t = threadIdx.x;
    ((float4*)gg)[t]       = ((const float4*)(g_gt + (size_t)b * 1024))[t];
    ((float4*)gg)[t + 256] = ((const float4*)(g_lt + (size_t)b * 1024))[t];
#pragma unroll
    for (int q = 0; q < 4; ++q) {
        int e = t + 256 * q;               // 1024 float4 = 32 rows x 128 cols
        int row = e >> 5, c4 = (e & 31) * 4;
        float4 v = *(const float4*)(x + (size_t)(b * NN + row) * DD + dc + c4);
        *(float4*)&xs[row][c4] = v;
        ushort4 o;
        o.x = f2bf(v.x); o.y = f2bf(v.y); o.z = f2bf(v.z); o.w = f2bf(v.w);
        *(ushort4*)(node0 + (size_t)(b * NN + row) * DD + dc + c4) = o;
    }
    __syncthreads();
#pragma unroll
    for (int gi = 0; gi < 2; ++gi) {
        unsigned short* O = gi ? t2 : t1;
#pragma unroll
        for (int it = 0; it < 4; ++it) {
            int task = it * 256 + t;       // 1024: n(32) x dq(32)
            int n = task >> 5, dq = task & 31;
            f32x4 r = {0.f, 0.f, 0.f, 0.f};
#pragma unroll
            for (int m = 0; m < NN; ++m)
                r += gg[gi][n][m] * *(const f32x4*)(&xs[m][dq * 4]);
            ushort4 ov;
            ov.x = f2bf(r.x); ov.y = f2bf(r.y); ov.z = f2bf(r.z); ov.w = f2bf(r.w);
            *(ushort4*)(O + (size_t)(b * NN + n) * DD + dc + dq * 4) = ov;
        }
    }
}

// ---------------------------------------------------------------------------
// MFMA GEMM, 64x128 tile, BK=64, double-buffered 2-phase K-loop.
// 4 waves (each 32x64 via 2x4 MFMA 16x16x32).
//  GATE: gate = sigmoid(A1@W1+A2@W2+bias); out = gate*gin1+(1-gate)*gin2
//  EMIX=1: out = bf16( G1 @ relu(A@W^T + bias) )     (stage-A + mix fused)
//  EMIX=2: out = relu(...); out2 = G1@out; out3 = G2@out   (out-GEMM h0)
//  else:   out = relu(A@W^T (+A2@W2^T) + bias)
// LDS staging swizzle: row r (128 B), slot s at pos p = s ^ (r&7).
// ---------------------------------------------------------------------------
struct GA {
    const unsigned short* A1; const unsigned short* W1;
    const unsigned short* A2; const unsigned short* W2;
    const float* bias;
    const unsigned short* gin1; const unsigned short* gin2;
    const float* G1; const float* G2;
    unsigned short* out; unsigned short* out2; unsigned short* out3;
};

template <bool DUAL, bool GATE, int EMIX>
__global__ __launch_bounds__(256) void mgemm_k(GA a0, GA a1) {
    GA g = (blockIdx.z == 0) ? a0 : a1;
    constexpr int LDSB = 49152 + (EMIX == 1 ? 8192 : EMIX == 2 ? 16384 : 0);
    __shared__ __align__(16) char lds[LDSB];
    unsigned short* Ab = (unsigned short*)lds;            // 2 bufs x 4096 shorts
    unsigned short* Bb = (unsigned short*)(lds + 16384);  // 2 bufs x 8192 shorts
    float* gsh = (float*)(lds + 49152);
    const int tid = threadIdx.x;
    const int lane = tid & 63;
    const int wave = tid >> 6;
    const int wr = wave & 1, wc = wave >> 1;
    const int bm = blockIdx.x * 64, bn = blockIdx.y * 128;

    if (EMIX >= 1) {
        const float4* g1 = (const float4*)(g.G1 + (size_t)(bm >> 5) * 1024);
        ((float4*)gsh)[tid] = g1[tid];
        ((float4*)gsh)[tid + 256] = g1[tid + 256];
        if (EMIX == 2) {
            const float4* g2v = (const float4*)(g.G2 + (size_t)(bm >> 5) * 1024);
            ((float4*)(gsh + 2048))[tid] = g2v[tid];
            ((float4*)(gsh + 2048))[tid + 256] = g2v[tid + 256];
        }
    }

    f32x4 acc[2][4];
#pragma unroll
    for (int i = 0; i < 2; ++i)
#pragma unroll
        for (int j = 0; j < 4; ++j) {
            acc[i][j].x = 0.f; acc[i][j].y = 0.f; acc[i][j].z = 0.f; acc[i][j].w = 0.f;
        }

    // staging geometry: entry e (16B) at LDS byte e*16; row r=e>>3, pos=e&7
    // holds global k-slot s = pos ^ (r&7).
    // A tile 64x64 shorts = 512 entries (2/thread); B tile 128x64 = 1024 (4/thread).
    const int rA0 = tid >> 3,          sA0 = (tid & 7) ^ (rA0 & 7);
    const int rA1 = (tid + 256) >> 3,  sA1 = (tid & 7) ^ (rA1 & 7);
    int rB[4], sB[4];
#pragma unroll
    for (int q = 0; q < 4; ++q) {
        int e = tid + 256 * q;
        rB[q] = e >> 3;
        sB[q] = (tid & 7) ^ (rB[q] & 7);
    }

    // fragment LDS offsets (shorts, within one buffer)
    int aoff[2][2], boff[2][4];
#pragma unroll
    for (int t = 0; t < 2; ++t) {
        int sl = t * 4 + (lane >> 4);
        int p = sl ^ (lane & 7);
#pragma unroll
        for (int i = 0; i < 2; ++i) {
            int m = wr * 32 + i * 16 + (lane & 15);
            aoff[t][i] = m * 64 + p * 8;
        }
#pragma unroll
        for (int j = 0; j < 4; ++j) {
            int n = wc * 64 + j * 16 + (lane & 15);
            boff[t][j] = n * 64 + p * 8;
        }
    }

    auto STAGE = [&](int ks, int c) {
        const unsigned short* A = (DUAL && ks >= 8) ? g.A2 : g.A1;
        const unsigned short* W = (DUAL && ks >= 8) ? g.W2 : g.W1;
        const int k0 = (ks & 7) * 64;
        g2l16(A + (size_t)(bm + rA0) * DD + k0 + sA0 * 8, Ab + c * 4096 + tid * 8);
        g2l16(A + (size_t)(bm + rA1) * DD + k0 + sA1 * 8,
              Ab + c * 4096 + (tid + 256) * 8);
#pragma unroll
        for (int q = 0; q < 4; ++q)
            g2l16(W + (size_t)(bn + rB[q]) * DD + k0 + sB[q] * 8,
                  Bb + c * 8192 + (tid + 256 * q) * 8);
    };

    const int NK = DUAL ? 16 : 8;
    STAGE(0, 0);
    __syncthreads();
    int cur = 0;
    for (int ks = 0; ks < NK; ++ks) {
        if (ks + 1 < NK) STAGE(ks + 1, cur ^ 1);
        const unsigned short* Ac = Ab + cur * 4096;
        const unsigned short* Bc = Bb + cur * 8192;
        bf16x8 af[2][2], bf_[2][4];
#pragma unroll
        for (int t = 0; t < 2; ++t) {
#pragma unroll
            for (int i = 0; i < 2; ++i) af[t][i] = *(const bf16x8*)(Ac + aoff[t][i]);
#pragma unroll
            for (int j = 0; j < 4; ++j) bf_[t][j] = *(const bf16x8*)(Bc + boff[t][j]);
        }
#pragma unroll
        for (int t = 0; t < 2; ++t)
#pragma unroll
            for (int i = 0; i < 2; ++i)
#pragma unroll
                for (int j = 0; j < 4; ++j)
                    acc[i][j] = __builtin_amdgcn_mfma_f32_16x16x32_bf16(
                        af[t][i], bf_[t][j], acc[i][j], 0, 0, 0);
        __syncthreads();
        cur ^= 1;
    }

    if (EMIX == 0) {
#pragma unroll
        for (int i = 0; i < 2; ++i) {
            int row = bm + wr * 32 + i * 16 + (lane >> 4) * 4;
#pragma unroll
            for (int j = 0; j < 4; ++j) {
                int col = bn + wc * 64 + j * 16 + (lane & 15);
                float bv = g.bias[col];
#pragma unroll
                for (int rg = 0; rg < 4; ++rg) {
                    float v = acc[i][j][rg] + bv;
                    size_t idx = (size_t)(row + rg) * DD + col;
                    if (GATE) {
                        float gg = 1.f / (1.f + __expf(-v));
                        float x1 = bf2f(g.gin1[idx]);
                        float x2 = bf2f(g.gin2[idx]);
                        g.out[idx] = f2bf(gg * x1 + (1.f - gg) * x2);
                    } else {
                        g.out[idx] = f2bf(fmaxf(v, 0.f));
                    }
                }
            }
        }
    } else {
        // stage relu(acc+bias) tile (64x128 fp32 = 32 KB, overlays staging bufs;
        // safe: final K-loop barrier already passed)
        float* S = (float*)lds;
#pragma unroll
        for (int i = 0; i < 2; ++i) {
            int lrow = wr * 32 + i * 16 + (lane >> 4) * 4;
#pragma unroll
            for (int j = 0; j < 4; ++j) {
                int lcol = wc * 64 + j * 16 + (lane & 15);
                float bv = g.bias[bn + lcol];
#pragma unroll
                for (int rg = 0; rg < 4; ++rg) {
                    float v = fmaxf(acc[i][j][rg] + bv, 0.f);
                    S[(lrow + rg) * 128 + lcol] = v;
                    if (EMIX == 2)
                        g.out[(size_t)(bm + lrow + rg) * DD + bn + lcol] = f2bf(v);
                }
            }
        }
        __syncthreads();
        const int ngi = (EMIX == 2) ? 2 : 1;
#pragma unroll
        for (int gi = 0; gi < ngi; ++gi) {
            unsigned short* O = (EMIX == 2) ? (gi ? g.out3 : g.out2) : g.out;
            const float* gb = gsh + gi * 2048;
#pragma unroll
            for (int it = 0; it < 8; ++it) {
                int task = it * 256 + tid;     // 2048: n(64) x dq(32)
                int n = task >> 5, dq = task & 31;
                int bt = n >> 5, nl = n & 31;
                const float* gr = gb + bt * 1024 + nl * 32;   // broadcast per half-wave
                const float* Sb = S + bt * 32 * 128 + dq * 4;
                f32x4 r = {0.f, 0.f, 0.f, 0.f};
#pragma unroll
                for (int m = 0; m < NN; ++m)
                    r += gr[m] * *(const f32x4*)(Sb + m * 128);
                ushort4 ov;
                ov.x = f2bf(r.x); ov.y = f2bf(r.y); ov.z = f2bf(r.z); ov.w = f2bf(r.w);
                *(ushort4*)(O + (size_t)(bm + n) * DD + bn + dq * 4) = ov;
            }
        }
    }
}

// ---------------------------------------------------------------------------
// Outputs: gnn_info + partial max (y<16, vectorized float4) and
// num_embedding (y in [16,20), quarter per block)
// ---------------------------------------------------------------------------
__global__ __launch_bounds__(256) void gnn_k(const float* __restrict__ enc,
                                             const unsigned short* __restrict__ node,
                                             const int* __restrict__ slot,
                                             const float* __restrict__ num_enc,
                                             float* __restrict__ out_gnn,
                                             float* __restrict__ out_nemb,
                                             float* __restrict__ partial) {
    int b = blockIdx.x;
    int t = threadIdx.x;
    if (blockIdx.y >= 16) {
        int q = blockIdx.y - 16;
        size_t base = (size_t)b * NN * DD + (size_t)q * (NN * DD / 4);
        for (int it = 0; it < 4; ++it) {
            size_t i = base + (size_t)(it * 256 + t) * 4;
            float4 a = *(const float4*)(num_enc + i);
            ushort4 nb = *(const ushort4*)(node + i);
            float4 r;
            r.x = a.x + bf2f(nb.x);
            r.y = a.y + bf2f(nb.y);
            r.z = a.z + bf2f(nb.z);
            r.w = a.w + bf2f(nb.w);
            *(float4*)(out_nemb + i) = r;
        }
        return;
    }
    __shared__ int sl[32];
    __shared__ float4 red[128];
    int s0 = blockIdx.y * 32;
    if (t < 32) sl[t] = slot[b * SS + s0 + t];
    __syncthreads();
    const int dv = (t & 127) * 4;
    const int sh = t >> 7;
    float4 mx = {-INFINITY, -INFINITY, -INFINITY, -INFINITY};
#pragma unroll 4
    for (int i = 0; i < 16; ++i) {
        int sloc = sh * 16 + i;
        int s = s0 + sloc;
        int n = sl[sloc];
        size_t ebase = ((size_t)s * BB + b) * DD + dv;
        float4 v = *(const float4*)(enc + ebase);
        if (n >= 0) {
            ushort4 nb = *(const ushort4*)(node + ((size_t)b * NN + n) * DD + dv);
            v.x += bf2f(nb.x);
            v.y += bf2f(nb.y);
            v.z += bf2f(nb.z);
            v.w += bf2f(nb.w);
        }
        *(float4*)(out_gnn + ebase) = v;
        mx.x = fmaxf(mx.x, v.x);
        mx.y = fmaxf(mx.y, v.y);
        mx.z = fmaxf(mx.z, v.z);
        mx.w = fmaxf(mx.w, v.w);
    }
    if (sh == 1) red[t & 127] = mx;
    __syncthreads();
    if (sh == 0) {
        float4 o = red[t];
        mx.x = fmaxf(mx.x, o.x);
        mx.y = fmaxf(mx.y, o.y);
        mx.z = fmaxf(mx.z, o.z);
        mx.w = fmaxf(mx.w, o.w);
        *(float4*)(partial + ((size_t)b * 16 + blockIdx.y) * DD + dv) = mx;
    }
}

__global__ void pmax_k(const float* __restrict__ partial, float* __restrict__ out_prob) {
    int i = blockIdx.x * 256 + threadIdx.x;
    if (i >= BB * DD) return;
    int b = i >> 9, d = i & 511;
    float m = -INFINITY;
    for (int c = 0; c < 16; ++c) m = fmaxf(m, partial[((size_t)b * 16 + c) * DD + d]);
    out_prob[i] = m;
}

// ---------------------------------------------------------------------------
// Host launch
// ---------------------------------------------------------------------------
extern "C" void kernel_launch(void* const* d_in, const int* in_sizes, int n_in,
                              void* d_out, int out_size, void* d_ws, size_t ws_size,
                              hipStream_t stream) {
    const float* enc     = (const float*)d_in[0];
    const float* num_enc = (const float*)d_in[1];
    const int*   pos     = (const int*)d_in[2];
    const int*   order   = (const int*)d_in[3];
    const float* w_n1a = (const float*)d_in[4];  const float* b_n1a = (const float*)d_in[5];
    const float* w_n1b = (const float*)d_in[6];  const float* b_n1b = (const float*)d_in[7];
    const float* w_n2a = (const float*)d_in[8];  const float* b_n2a = (const float*)d_in[9];
    const float* w_n2b = (const float*)d_in[10]; const float* b_n2b = (const float*)d_in[11];
    const float* w_g   = (const float*)d_in[12]; const float* b_g   = (const float*)d_in[13];
    const float* w_o   = (const float*)d_in[14]; const float* b_o   = (const float*)d_in[15];

    char* wp = (char*)d_ws;
    float* g_gt = (float*)wp;        wp += (size_t)BB * NN * NN * 4;
    float* g_lt = (float*)wp;        wp += (size_t)BB * NN * NN * 4;
    float* partial = (float*)wp;     wp += (size_t)BB * 16 * DD * 4;
    int* slot = (int*)wp;            wp += (size_t)BB * SS * 4;
    unsigned short* Wt = (unsigned short*)wp;    wp += (size_t)16 * DSQ * 2;
    unsigned short* node0 = (unsigned short*)wp; wp += (size_t)MM * DD * 2;
    unsigned short* nodeA = (unsigned short*)wp; wp += (size_t)MM * DD * 2;
    unsigned short* nodeB = (unsigned short*)wp; wp += (size_t)MM * DD * 2;
    unsigned short* ni1 = (unsigned short*)wp;   wp += (size_t)MM * DD * 2;
    unsigned short* ni2 = (unsigned short*)wp;   wp += (size_t)MM * DD * 2;
    unsigned short* t1 = (unsigned short*)wp;    wp += (size_t)MM * DD * 2;
    unsigned short* t2 = (unsigned short*)wp;    wp += (size_t)MM * DD * 2;

    float* out_gnn  = (float*)d_out;
    float* out_nemb = out_gnn + (size_t)SS * BB * DD;
    float* out_prob = out_nemb + (size_t)BB * NN * DD;

    // Setup (3 dispatches)
    adj_k<<<BB, 256, 0, stream>>>(order, pos, g_gt, g_lt, slot);

    WSfull wsrc;
    const float* srcs[12] = {w_n1a, w_n1b, w_n2a, w_n2b, w_o, w_o + DSQ,
                             w_n1a + DSQ, w_n1b + DSQ, w_n2a + DSQ, w_n2b + DSQ,
                             w_o + 2 * DSQ, w_o + 3 * DSQ};
    int slots[12] = {0, 1, 2, 3, 6, 7, 8, 9, 10, 11, 14, 15};
    for (int i = 0; i < 12; ++i) { wsrc.s[i] = srcs[i]; wsrc.slot[i] = slots[i]; }
    wsrc.w_g = w_g;
    wprep_k<<<dim3(14, 64), 256, 0, stream>>>(wsrc, Wt);
    convmix_k<<<dim3(BB, 4), 256, 0, stream>>>(num_enc, g_gt, g_lt, node0, t1, t2);

    dim3 ggrid(MM / 64, DD / 128, 2);   // paired single-source GEMMs: 512 blocks
    dim3 sgrid(MM / 64, DD / 128, 1);   // DUAL GEMMs: 256 blocks

    for (int h = 0; h < HH; ++h) {
        const unsigned short* Wh = Wt + (size_t)h * 8 * DSQ;
        const unsigned short* nodeIn = (h == 0) ? node0 : nodeA;

        // stage A (+mix epilogue): zb1 = g_gt@relu(t1@W1a+b); zb2 = g_lt@relu(t2@W2a+b)
        GA sa0 = {t1, Wh + 0 * DSQ, nullptr, nullptr, b_n1a + h * DD,
                  nullptr, nullptr, g_gt, nullptr, ni1, nullptr, nullptr};
        GA sa1 = {t2, Wh + 2 * DSQ, nullptr, nullptr, b_n2a + h * DD,
                  nullptr, nullptr, g_lt, nullptr, ni2, nullptr, nullptr};
        mgemm_k<false, false, 1><<<ggrid, 256, 0, stream>>>(sa0, sa1);

        // stage B: t1 = relu(zb1@W1b+b); t2 = relu(zb2@W2b+b)
        GA sb0 = {ni1, Wh + 1 * DSQ, nullptr, nullptr, b_n1b + h * DD,
                  nullptr, nullptr, nullptr, nullptr, t1, nullptr, nullptr};
        GA sb1 = {ni2, Wh + 3 * DSQ, nullptr, nullptr, b_n2b + h * DD,
                  nullptr, nullptr, nullptr, nullptr, t2, nullptr, nullptr};
        mgemm_k<false, false, 0><<<ggrid, 256, 0, stream>>>(sb0, sb1);

        // gate: info = gate*t1 + (1-gate)*t2  -> ni1
        GA gg2 = {t1, Wh + 4 * DSQ, t2, Wh + 5 * DSQ, b_g + h * DD,
                  t1, t2, nullptr, nullptr, ni1, nullptr, nullptr};
        mgemm_k<true, true, 0><<<sgrid, 256, 0, stream>>>(gg2, gg2);

        // out: node = relu(x@Wo_a + info@Wo_b + b); h=0 also emits next-hop mixes
        if (h == 0) {
            GA go = {nodeIn, Wh + 6 * DSQ, ni1, Wh + 7 * DSQ, b_o + h * DD,
                     nullptr, nullptr, g_gt, g_lt, nodeA, t1, t2};
            mgemm_k<true, false, 2><<<sgrid, 256, 0, stream>>>(go, go);
        } else {
            GA go = {nodeIn, Wh + 6 * DSQ, ni1, Wh + 7 * DSQ, b_o + h * DD,
                     nullptr, nullptr, nullptr, nullptr, nodeB, nullptr, nullptr};
            mgemm_k<true, false, 0><<<sgrid, 256, 0, stream>>>(go, go);
        }
    }
    const unsigned short* nodeF = nodeB;

    // Outputs (2 dispatches)
    gnn_k<<<dim3(BB, 20), 256, 0, stream>>>(enc, nodeF, slot, num_enc,
                                            out_gnn, out_nemb, partial);
    pmax_k<<<(BB * DD) / 256, 256, 0, stream>>>(partial, out_prob);
}